// Round 7
// baseline (599.865 us; speedup 1.0000x reference)
//
#include <hip/hip_runtime.h>
#include <hip/hip_bf16.h>

// out[b,h,w,h',w'] = dot(q[b,h,w,:], rel_h[h'-h+63,:]) + dot(q[b,h,w,:], rel_w[w'-w+63,:])
//
// Factored form: per (b,h,w) "slab", compute Lh[64], Lw[64] (128 length-64
// dots), then broadcast-add into a contiguous 64x64 fp32 tile (16 KiB).
// Pure store-BW-bound: 512 MiB out vs 8 MiB q in.
//
// Each block owns SLABS=4 consecutive slabs: coalesced q stage (256 floats),
// 512 dots = 2/thread across all 256 threads, 2 barriers per 64 KiB written,
// nontemporal float4 stores (write-once data, skip L2 allocate).
//
// NOTE: __builtin_nontemporal_store requires a clang native vector type,
// not HIP's float4 class -> use ext_vector_type(4).

#define D 64
#define SLABS 4

typedef float f32x4 __attribute__((ext_vector_type(4)));

__global__ __launch_bounds__(256) void relpe_kernel(
    const float* __restrict__ q,
    const float* __restrict__ rel_h,
    const float* __restrict__ rel_w,
    float* __restrict__ out) {
    const int base = blockIdx.x * SLABS;   // first slab id (b*4096 + h*64 + w)
    const int t = threadIdx.x;

    __shared__ __align__(16) float qs[SLABS][D];
    __shared__ __align__(16) float Lh[SLABS][64];
    __shared__ __align__(16) float Lw[SLABS][64];

    // stage q for 4 slabs: 256 contiguous floats, one per thread
    qs[t >> 6][t & 63] = q[(size_t)base * D + t];
    __syncthreads();

    // 512 dots (4 slabs x (64 Lh + 64 Lw)), 2 per thread
#pragma unroll
    for (int i = 0; i < 2; ++i) {
        const int id   = t + i * 256;      // 0..511
        const int s    = id >> 7;          // slab 0..3
        const int j    = id & 63;          // output index h' or w'
        const bool isH = ((id >> 6) & 1) == 0;
        const int sid  = base + s;
        const int w = sid & 63;
        const int h = (sid >> 6) & 63;
        const float* __restrict__ rel =
            isH ? (rel_h + (size_t)(j - h + 63) * D)
                : (rel_w + (size_t)(j - w + 63) * D);
        const float* __restrict__ qv = qs[s];
        float acc = 0.f;
#pragma unroll
        for (int d = 0; d < D; d += 4) {
            const f32x4 r = *reinterpret_cast<const f32x4*>(rel + d);
            acc += qv[d + 0] * r.x;
            acc += qv[d + 1] * r.y;
            acc += qv[d + 2] * r.z;
            acc += qv[d + 3] * r.w;
        }
        if (isH) Lh[s][j] = acc; else Lw[s][j] = acc;
    }
    __syncthreads();

    // write 4 slabs x 16 KiB, coalesced float4, nontemporal (write-once)
#pragma unroll
    for (int s = 0; s < SLABS; ++s) {
        f32x4* __restrict__ op =
            reinterpret_cast<f32x4*>(out + (size_t)(base + s) * 4096);
        const float* __restrict__ lh = Lh[s];
        const float* __restrict__ lw = Lw[s];
#pragma unroll
        for (int i = 0; i < 4; ++i) {
            const int idx = t + i * 256;   // float4 index in slab, 0..1023
            const int hp  = idx >> 4;      // h' (16 float4 per row)
            const int wq  = idx & 15;      // float4 within row
            const float a = lh[hp];
            const f32x4 b = *reinterpret_cast<const f32x4*>(&lw[wq * 4]);
            f32x4 v;
            v.x = a + b.x;
            v.y = a + b.y;
            v.z = a + b.z;
            v.w = a + b.w;
            __builtin_nontemporal_store(v, op + idx);
        }
    }
}

extern "C" void kernel_launch(void* const* d_in, const int* in_sizes, int n_in,
                              void* d_out, int out_size, void* d_ws, size_t ws_size,
                              hipStream_t stream) {
    const float* q     = (const float*)d_in[0];   // [8,64,64,64]
    const float* rel_h = (const float*)d_in[1];   // [127,64]
    const float* rel_w = (const float*)d_in[2];   // [127,64]
    float* out = (float*)d_out;                   // [8,64,64,64,64]

    const int nblocks = (8 * 64 * 64) / SLABS;    // 8192 blocks x 4 slabs
    relpe_kernel<<<nblocks, 256, 0, stream>>>(q, rel_h, rel_w, out);
}

// Round 16
// 559.552 us; speedup vs baseline: 1.0720x; 1.0720x over previous
//
#include <hip/hip_runtime.h>
#include <hip/hip_bf16.h>

// out[b,h,w,h',w'] = dot(q[b,h,w,:], rel_h[h'-h+63,:]) + dot(q[b,h,w,:], rel_w[w'-w+63,:])
//
// Factored form; per block: 4 consecutive (b,h,w) slabs (same h, w0=4k).
// Phase A: stage rel_h rows (63-h..126-h) [64 rows] and rel_w rows
//          (60-w0..126-w0) [67 rows] into LDS with +1 padding (stride 65
//          floats -> bank=(row+d)%32, conflict-free). Compute 512 dots,
//          q via wave-uniform (readfirstlane) pointer -> scalar loads.
// Phase B: broadcast-add Lh[hp]+Lw[wq], stream 4x16KiB with plain float4
//          stores (fill kernel proves plain stores sustain 6.2 TB/s).

#define D 64
#define SLABS 4

typedef float f32x4 __attribute__((ext_vector_type(4)));

__global__ __launch_bounds__(256) void relpe_kernel(
    const float* __restrict__ q,
    const float* __restrict__ rel_h,
    const float* __restrict__ rel_w,
    float* __restrict__ out) {
    const int base = blockIdx.x * SLABS;   // slab id = b*4096 + h*64 + w
    const int w0 = base & 63;              // multiple of 4; slabs share h
    const int h  = (base >> 6) & 63;
    const int t  = threadIdx.x;

    __shared__ __align__(16) float relh_s[64 * 65];   // row r = table row (63-h)+r
    __shared__ __align__(16) float relw_s[67 * 65];   // row r = table row (60-w0)+r
    __shared__ __align__(16) float Lh[SLABS][64];
    __shared__ __align__(16) float Lw[SLABS][64];

    // ---- Phase A0: stage rel tables into padded LDS (coalesced f32x4 loads)
    {
        const float* __restrict__ srch = rel_h + (63 - h) * D;
        for (int idx = t; idx < 64 * 16; idx += 256) {        // 64 rows x 16 quads
            const int r = idx >> 4, c = (idx & 15) * 4;
            const f32x4 v = *reinterpret_cast<const f32x4*>(srch + r * D + c);
            float* dst = &relh_s[r * 65 + c];
            dst[0] = v.x; dst[1] = v.y; dst[2] = v.z; dst[3] = v.w;
        }
        const float* __restrict__ srcw = rel_w + (60 - w0) * D;
        for (int idx = t; idx < 67 * 16; idx += 256) {        // 67 rows x 16 quads
            const int r = idx >> 4, c = (idx & 15) * 4;
            const f32x4 v = *reinterpret_cast<const f32x4*>(srcw + r * D + c);
            float* dst = &relw_s[r * 65 + c];
            dst[0] = v.x; dst[1] = v.y; dst[2] = v.z; dst[3] = v.w;
        }
    }
    __syncthreads();

    // ---- Phase A1: 512 dots, 2 per thread. s and isH are wave-uniform.
#pragma unroll
    for (int i = 0; i < 2; ++i) {
        const int id = t + i * 256;                 // 0..511
        const int s  = __builtin_amdgcn_readfirstlane((id >> 7) & 3);
        const bool isH = ((id >> 6) & 1) == 0;      // wave-uniform
        const int j = id & 63;                      // lane-varying
        // q row: wave-uniform address -> scalar loads feeding FMA
        const float* __restrict__ qg = q + (size_t)(base + s) * D;
        // rel row in LDS: H -> local row j ; W -> local row j - s + 3
        const float* __restrict__ rl =
            isH ? &relh_s[j * 65] : &relw_s[(j - s + 3) * 65];
        float a0 = 0.f, a1 = 0.f, a2 = 0.f, a3 = 0.f;
#pragma unroll
        for (int d = 0; d < D; d += 4) {
            a0 += qg[d + 0] * rl[d + 0];
            a1 += qg[d + 1] * rl[d + 1];
            a2 += qg[d + 2] * rl[d + 2];
            a3 += qg[d + 3] * rl[d + 3];
        }
        const float acc = (a0 + a1) + (a2 + a3);
        if (isH) Lh[s][j] = acc; else Lw[s][j] = acc;
    }
    __syncthreads();

    // ---- Phase B: write 4 slabs x 16 KiB, coalesced plain float4 stores
#pragma unroll
    for (int s = 0; s < SLABS; ++s) {
        f32x4* __restrict__ op =
            reinterpret_cast<f32x4*>(out + (size_t)(base + s) * 4096);
        const float* __restrict__ lh = Lh[s];
        const float* __restrict__ lw = Lw[s];
#pragma unroll
        for (int i = 0; i < 4; ++i) {
            const int idx = t + i * 256;   // float4 index in slab, 0..1023
            const int hp  = idx >> 4;      // h' (16 float4 per row)
            const int wq  = idx & 15;      // float4 within row
            const float a = lh[hp];
            const f32x4 b = *reinterpret_cast<const f32x4*>(&lw[wq * 4]);
            f32x4 v;
            v.x = a + b.x;
            v.y = a + b.y;
            v.z = a + b.z;
            v.w = a + b.w;
            op[idx] = v;
        }
    }
}

extern "C" void kernel_launch(void* const* d_in, const int* in_sizes, int n_in,
                              void* d_out, int out_size, void* d_ws, size_t ws_size,
                              hipStream_t stream) {
    const float* q     = (const float*)d_in[0];   // [8,64,64,64]
    const float* rel_h = (const float*)d_in[1];   // [127,64]
    const float* rel_w = (const float*)d_in[2];   // [127,64]
    float* out = (float*)d_out;                   // [8,64,64,64,64]

    const int nblocks = (8 * 64 * 64) / SLABS;    // 8192 blocks x 4 slabs
    relpe_kernel<<<nblocks, 256, 0, stream>>>(q, rel_h, rel_w, out);
}